// Round 3
// baseline (313.361 us; speedup 1.0000x reference)
//
#include <hip/hip_runtime.h>
#include <math.h>

// Shapes: x (B,N,64) fp32, mask (B,N), cent (256,64) fp32.
// out = concat( graph_dist (B,256), dist (B,N,256) ), fp32.
#define E_DIM 64
#define C_DIM 256
#define EPS_F 1e-6f
#define LN2_F 0.69314718056f
#define TP    68            // padded LDS row stride (dwords): 2-way bank alias only

typedef __attribute__((ext_vector_type(8))) short short8;   // 8 bf16 = 4 VGPRs
typedef __attribute__((ext_vector_type(4))) float f32x4;

__device__ __forceinline__ unsigned short f2bf(float f) {
    unsigned int u = __float_as_uint(f);
    u += 0x7FFFu + ((u >> 16) & 1u);     // round-to-nearest-even
    return (unsigned short)(u >> 16);
}

__device__ __forceinline__ short8 pack8(float4 a, float4 b) {
    short8 h;
    h[0] = (short)f2bf(a.x); h[1] = (short)f2bf(a.y);
    h[2] = (short)f2bf(a.z); h[3] = (short)f2bf(a.w);
    h[4] = (short)f2bf(b.x); h[5] = (short)f2bf(b.y);
    h[6] = (short)f2bf(b.z); h[7] = (short)f2bf(b.w);
    return h;
}

// ws layout (bytes):
//   [0, 32768)     : B-fragments, short8 F[(ct16*2+kf)*64 + lane]
//   [32768, 33792) : c2[256]
//   [33792, 34816) : rd2[256]  = 2/(1-c2)
//   [34816, ...)   : inv_masksum[B]
#define WS_F    0
#define WS_C2   32768
#define WS_RD2  33792
#define WS_INVM 34816

// Block 0: centroid conversion + stats. Blocks 1..B: per-batch 1/sum(mask)
// and zero-init of graph_acc row b (replaces the hipMemsetAsync graph node).
__global__ __launch_bounds__(C_DIM) void cdist_pre(
    const float* __restrict__ cent,
    const float* __restrict__ mask,
    unsigned char* __restrict__ ws,
    float* __restrict__ graph_acc,
    int N)
{
    const int t = threadIdx.x;
    if (blockIdx.x == 0) {
        float r[E_DIM];
        const float* cr = cent + t * E_DIM;
        #pragma unroll
        for (int e = 0; e < E_DIM; e += 4) {
            float4 v = *reinterpret_cast<const float4*>(cr + e);
            r[e] = v.x; r[e+1] = v.y; r[e+2] = v.z; r[e+3] = v.w;
        }
        float c2 = 0.f;
        #pragma unroll
        for (int e = 0; e < E_DIM; ++e) c2 = fmaf(r[e], r[e], c2);
        ((float*)(ws + WS_C2))[t]  = c2;
        ((float*)(ws + WS_RD2))[t] = 2.f / (1.f - c2);

        const int ct16 = t >> 4, l15 = t & 15;
        short8* F = (short8*)(ws + WS_F);
        #pragma unroll
        for (int kf = 0; kf < 2; ++kf) {
            #pragma unroll
            for (int q = 0; q < 4; ++q) {
                short8 h;
                #pragma unroll
                for (int j = 0; j < 8; ++j)
                    h[j] = (short)f2bf(r[kf * 32 + q * 8 + j]);
                F[(ct16 * 2 + kf) * 64 + 16 * q + l15] = h;
            }
        }
    } else {
        const int b = blockIdx.x - 1;
        graph_acc[b * C_DIM + t] = 0.f;
        float s = 0.f;
        for (int n = t; n < N; n += C_DIM) s += mask[(size_t)b * N + n];
        #pragma unroll
        for (int off = 32; off > 0; off >>= 1) s += __shfl_down(s, off, 64);
        __shared__ float partial[4];
        if ((t & 63) == 0) partial[t >> 6] = s;
        __syncthreads();
        if (t == 0) {
            float tot = partial[0] + partial[1] + partial[2] + partial[3];
            ((float*)(ws + WS_INVM))[b] = 1.f / tot;
        }
    }
}

// Main: 256 threads (4 waves). Each block covers NT_TILES*16 rows x 256 cols.
// Wave w owns cols [w*64, w*64+64). 2-deep prefetch pipeline (slot rt&1,
// static after unroll-2). 64-row blocks -> 2048 blocks = 8 blocks/CU with
// __launch_bounds__(256,8): VGPR<=64, LDS 17.4KB*8=139KB, 2048 thr = CU max.
// All three occupancy limits line up at 8 blocks/CU = 8 waves/SIMD for
// latency hiding (round-2 counters: 3 waves/SIMD, 90% stalled).
template<int NT_TILES>
__global__ __launch_bounds__(256, 8) void cdist_mfma(
    const float* __restrict__ x,
    const float* __restrict__ mask,
    const unsigned char* __restrict__ ws,
    float*       __restrict__ graph_acc,  // (B,C), pre-zeroed
    float*       __restrict__ dist,       // (B,N,C)
    int N)
{
    const int tid  = threadIdx.x;
    const int w    = tid >> 6;
    const int lane = tid & 63;
    const int l15  = lane & 15;
    const int q    = lane >> 4;
    const int n0   = blockIdx.x * (NT_TILES * 16);
    const int b    = blockIdx.y;

    __shared__ __align__(16) float sT[4][16 * TP];   // per-wave transpose tile

    const short8* F    = (const short8*)(ws + WS_F);
    const float*  c2w  = (const float*)(ws + WS_C2);
    const float*  rd2w = (const float*)(ws + WS_RD2);

    short8 bfrag[4][2];
    #pragma unroll
    for (int ct = 0; ct < 4; ++ct)
        #pragma unroll
        for (int kf = 0; kf < 2; ++kf)
            bfrag[ct][kf] = F[((w * 4 + ct) * 2 + kf) * 64 + lane];

    float c2v[4], rd2v[4], gsum[4];
    #pragma unroll
    for (int ct = 0; ct < 4; ++ct) {
        const int c = w * 64 + ct * 16 + l15;
        c2v[ct] = c2w[c]; rd2v[ct] = rd2w[c]; gsum[ct] = 0.f;
    }

    const size_t rowbase = (size_t)b * N + n0;
    float* sW = sT[w];

    // 2-deep prefetch: slots 0,1 hold tiles rt and rt+1
    float4 pv0[2], pv1[2], pv2[2], pv3[2];
    float  pmk[2];
    {
        const float* xr0 = x + (rowbase + l15) * E_DIM + q * 8;
        pv0[0] = *reinterpret_cast<const float4*>(xr0);
        pv1[0] = *reinterpret_cast<const float4*>(xr0 + 4);
        pv2[0] = *reinterpret_cast<const float4*>(xr0 + 32);
        pv3[0] = *reinterpret_cast<const float4*>(xr0 + 36);
        pmk[0] = mask[rowbase + l15];
        const float* xr1 = xr0 + 16 * E_DIM;
        pv0[1] = *reinterpret_cast<const float4*>(xr1);
        pv1[1] = *reinterpret_cast<const float4*>(xr1 + 4);
        pv2[1] = *reinterpret_cast<const float4*>(xr1 + 32);
        pv3[1] = *reinterpret_cast<const float4*>(xr1 + 36);
        pmk[1] = mask[rowbase + 16 + l15];
    }

    #pragma unroll 2
    for (int rt = 0; rt < NT_TILES; ++rt) {
        const int s = rt & 1;              // static after unroll-2
        const float4 u0 = pv0[s], u1 = pv1[s], u2 = pv2[s], u3 = pv3[s];
        const float  mkc = pmk[s];

        // exact fp32 row norm, tree-shaped (short dep chains)
        float sa = 0.f, sb = 0.f, sc = 0.f, sd = 0.f;
        sa = fmaf(u0.x, u0.x, sa); sa = fmaf(u0.y, u0.y, sa);
        sa = fmaf(u0.z, u0.z, sa); sa = fmaf(u0.w, u0.w, sa);
        sb = fmaf(u1.x, u1.x, sb); sb = fmaf(u1.y, u1.y, sb);
        sb = fmaf(u1.z, u1.z, sb); sb = fmaf(u1.w, u1.w, sb);
        sc = fmaf(u2.x, u2.x, sc); sc = fmaf(u2.y, u2.y, sc);
        sc = fmaf(u2.z, u2.z, sc); sc = fmaf(u2.w, u2.w, sc);
        sd = fmaf(u3.x, u3.x, sd); sd = fmaf(u3.y, u3.y, sd);
        sd = fmaf(u3.z, u3.z, sd); sd = fmaf(u3.w, u3.w, sd);
        float ss = (sa + sb) + (sc + sd);
        ss += __shfl_xor(ss, 16);
        ss += __shfl_xor(ss, 32);

        const float rbrow = __builtin_amdgcn_rcpf(1.f - ss);
        const float krow  = LN2_F * mkc;

        short8 a0 = pack8(u0, u1);
        short8 a1 = pack8(u2, u3);

        // refill slot s with tile rt+2 (u*/a* already extracted)
        if (rt + 2 < NT_TILES) {
            const float* xr = x + (rowbase + (rt + 2) * 16 + l15) * E_DIM + q * 8;
            pv0[s] = *reinterpret_cast<const float4*>(xr);
            pv1[s] = *reinterpret_cast<const float4*>(xr + 4);
            pv2[s] = *reinterpret_cast<const float4*>(xr + 32);
            pv3[s] = *reinterpret_cast<const float4*>(xr + 36);
            pmk[s] = mask[rowbase + (rt + 2) * 16 + l15];
        }

        f32x4 acc[4];
        #pragma unroll
        for (int ct = 0; ct < 4; ++ct) {
            f32x4 z = {0.f, 0.f, 0.f, 0.f};
            z = __builtin_amdgcn_mfma_f32_16x16x32_bf16(a0, bfrag[ct][0], z, 0, 0, 0);
            z = __builtin_amdgcn_mfma_f32_16x16x32_bf16(a1, bfrag[ct][1], z, 0, 0, 0);
            acc[ct] = z;
        }

        // per-row stats for this lane's 4 output rows (rows q*4+reg)
        float ar[4], rbr[4], kr[4];
        #pragma unroll
        for (int reg = 0; reg < 4; ++reg) {
            const int src = q * 4 + reg;
            ar[reg]  = __shfl(ss,    src);
            rbr[reg] = __shfl(rbrow, src);
            kr[reg]  = __shfl(krow,  src);
        }

        // epilogue -> LDS tile (row = q*4+reg, col = ct*16+l15)
        #pragma unroll
        for (int ct = 0; ct < 4; ++ct) {
            #pragma unroll
            for (int reg = 0; reg < 4; ++reg) {
                const float dot = acc[ct][reg];
                float sq = fmaf(-2.f, dot, ar[reg] + c2v[ct]);
                sq = fmaxf(sq, 0.f);
                float uu = fmaxf(sq * (rbr[reg] * rd2v[ct]), EPS_F);
                float t  = uu + __builtin_amdgcn_sqrtf(fmaf(uu, uu, uu + uu));
                const float d = __builtin_amdgcn_logf(1.f + t) * kr[reg];
                sW[(q * 4 + reg) * TP + ct * 16 + l15] = d;
                gsum[ct] += d;
            }
        }

        // drain LDS tile -> global, dwordx4, 256B-contiguous row segments
        #pragma unroll
        for (int i = 0; i < 4; ++i) {
            const int row2 = i * 4 + (lane >> 4);      // 0..15
            const int col2 = (lane & 15) * 4;          // 0..60
            float4 val = *reinterpret_cast<const float4*>(&sW[row2 * TP + col2]);
            *reinterpret_cast<float4*>(
                dist + (rowbase + rt * 16 + row2) * C_DIM + w * 64 + col2) = val;
        }
    }

    const float inv = ((const float*)(ws + WS_INVM))[b];
    #pragma unroll
    for (int ct = 0; ct < 4; ++ct) {
        float s = gsum[ct];
        s += __shfl_xor(s, 16);
        s += __shfl_xor(s, 32);
        if (q == 0)
            atomicAdd(&graph_acc[b * C_DIM + w * 64 + ct * 16 + l15], s * inv);
    }
}

extern "C" void kernel_launch(void* const* d_in, const int* in_sizes, int n_in,
                              void* d_out, int out_size, void* d_ws, size_t ws_size,
                              hipStream_t stream) {
    const float* x    = (const float*)d_in[0];
    const float* mask = (const float*)d_in[1];
    const float* cent = (const float*)d_in[2];
    float* out = (float*)d_out;

    // in_sizes = { B*N*E, B*N, C*E }; out_size = B*C + B*N*C
    const long long BN = in_sizes[1];
    const int E = in_sizes[0] / (int)BN;       // 64
    const int C = in_sizes[2] / E;             // 256
    const int B = (int)(((long long)out_size - BN * C) / C);
    const int N = (int)(BN / B);

    float* graph_acc = out;                    // (B,C)
    float* dist_out  = out + (size_t)B * C;    // (B,N,C)
    unsigned char* ws = (unsigned char*)d_ws;

    cdist_pre<<<dim3(B + 1), C_DIM, 0, stream>>>(cent, mask, ws, graph_acc, N);

    cdist_mfma<4><<<dim3(N / 64, B), 256, 0, stream>>>(
        x, mask, ws, graph_acc, dist_out, N);
}

// Round 4
// 208.774 us; speedup vs baseline: 1.5010x; 1.5010x over previous
//
#include <hip/hip_runtime.h>
#include <math.h>

// Shapes: x (B,N,64) fp32, mask (B,N), cent (256,64) fp32.
// out = concat( graph_dist (B,256), dist (B,N,256) ), fp32.
#define E_DIM 64
#define C_DIM 256
#define EPS_F 1e-6f
#define LN2_F 0.69314718056f
#define TP    68            // padded LDS row stride (dwords): 2-way bank alias only

typedef __attribute__((ext_vector_type(8))) short short8;   // 8 bf16 = 4 VGPRs
typedef __attribute__((ext_vector_type(4))) float f32x4;

__device__ __forceinline__ unsigned short f2bf(float f) {
    unsigned int u = __float_as_uint(f);
    u += 0x7FFFu + ((u >> 16) & 1u);     // round-to-nearest-even
    return (unsigned short)(u >> 16);
}

__device__ __forceinline__ short8 pack8(float4 a, float4 b) {
    short8 h;
    h[0] = (short)f2bf(a.x); h[1] = (short)f2bf(a.y);
    h[2] = (short)f2bf(a.z); h[3] = (short)f2bf(a.w);
    h[4] = (short)f2bf(b.x); h[5] = (short)f2bf(b.y);
    h[6] = (short)f2bf(b.z); h[7] = (short)f2bf(b.w);
    return h;
}

// ws layout (bytes):
//   [0, 32768)     : B-fragments, short8 F[(ct16*2+kf)*64 + lane]
//   [32768, 33792) : c2[256]
//   [33792, 34816) : rd2[256]  = 2/(1-c2)
//   [34816, ...)   : inv_masksum[B]
#define WS_F    0
#define WS_C2   32768
#define WS_RD2  33792
#define WS_INVM 34816

// Block 0: centroid conversion + stats. Blocks 1..B: per-batch 1/sum(mask)
// and zero-init of graph_acc row b (replaces the hipMemsetAsync graph node).
__global__ __launch_bounds__(C_DIM) void cdist_pre(
    const float* __restrict__ cent,
    const float* __restrict__ mask,
    unsigned char* __restrict__ ws,
    float* __restrict__ graph_acc,
    int N)
{
    const int t = threadIdx.x;
    if (blockIdx.x == 0) {
        float r[E_DIM];
        const float* cr = cent + t * E_DIM;
        #pragma unroll
        for (int e = 0; e < E_DIM; e += 4) {
            float4 v = *reinterpret_cast<const float4*>(cr + e);
            r[e] = v.x; r[e+1] = v.y; r[e+2] = v.z; r[e+3] = v.w;
        }
        float c2 = 0.f;
        #pragma unroll
        for (int e = 0; e < E_DIM; ++e) c2 = fmaf(r[e], r[e], c2);
        ((float*)(ws + WS_C2))[t]  = c2;
        ((float*)(ws + WS_RD2))[t] = 2.f / (1.f - c2);

        const int ct16 = t >> 4, l15 = t & 15;
        short8* F = (short8*)(ws + WS_F);
        #pragma unroll
        for (int kf = 0; kf < 2; ++kf) {
            #pragma unroll
            for (int q = 0; q < 4; ++q) {
                short8 h;
                #pragma unroll
                for (int j = 0; j < 8; ++j)
                    h[j] = (short)f2bf(r[kf * 32 + q * 8 + j]);
                F[(ct16 * 2 + kf) * 64 + 16 * q + l15] = h;
            }
        }
    } else {
        const int b = blockIdx.x - 1;
        graph_acc[b * C_DIM + t] = 0.f;
        float s = 0.f;
        for (int n = t; n < N; n += C_DIM) s += mask[(size_t)b * N + n];
        #pragma unroll
        for (int off = 32; off > 0; off >>= 1) s += __shfl_down(s, off, 64);
        __shared__ float partial[4];
        if ((t & 63) == 0) partial[t >> 6] = s;
        __syncthreads();
        if (t == 0) {
            float tot = partial[0] + partial[1] + partial[2] + partial[3];
            ((float*)(ws + WS_INVM))[b] = 1.f / tot;
        }
    }
}

// Main: 256 threads (4 waves). Each block covers NT_TILES*16 rows x 256 cols.
// Wave w owns cols [w*64, w*64+64). 2-deep prefetch pipeline (slot rt&1,
// static after unroll-2).
//
// Occupancy plan (round-3 lesson): do NOT force 8 waves/EU via launch_bounds
// — that squeezed the unified VGPR+AGPR budget to 32 arch-VGPRs and spilled
// ~500 MB to scratch (FETCH 266 MB / WRITE 416 MB). Instead: bounds(256,4)
// (compiler lands at 64 VGPR naturally, round-2-proven, no spills) + a
// 2048-block grid (64-row tiles) so the HW can co-schedule up to 8 blocks/CU
// (LDS 17.4KB*8=139KB<160KB, 2048 threads = CU max).
template<int NT_TILES>
__global__ __launch_bounds__(256, 4) void cdist_mfma(
    const float* __restrict__ x,
    const float* __restrict__ mask,
    const unsigned char* __restrict__ ws,
    float*       __restrict__ graph_acc,  // (B,C), pre-zeroed
    float*       __restrict__ dist,       // (B,N,C)
    int N)
{
    const int tid  = threadIdx.x;
    const int w    = tid >> 6;
    const int lane = tid & 63;
    const int l15  = lane & 15;
    const int q    = lane >> 4;
    const int n0   = blockIdx.x * (NT_TILES * 16);
    const int b    = blockIdx.y;

    __shared__ __align__(16) float sT[4][16 * TP];   // per-wave transpose tile

    const short8* F    = (const short8*)(ws + WS_F);
    const float*  c2w  = (const float*)(ws + WS_C2);
    const float*  rd2w = (const float*)(ws + WS_RD2);

    short8 bfrag[4][2];
    #pragma unroll
    for (int ct = 0; ct < 4; ++ct)
        #pragma unroll
        for (int kf = 0; kf < 2; ++kf)
            bfrag[ct][kf] = F[((w * 4 + ct) * 2 + kf) * 64 + lane];

    float c2v[4], rd2v[4], gsum[4];
    #pragma unroll
    for (int ct = 0; ct < 4; ++ct) {
        const int c = w * 64 + ct * 16 + l15;
        c2v[ct] = c2w[c]; rd2v[ct] = rd2w[c]; gsum[ct] = 0.f;
    }

    const size_t rowbase = (size_t)b * N + n0;
    float* sW = sT[w];

    // 2-deep prefetch: slots 0,1 hold tiles rt and rt+1
    float4 pv0[2], pv1[2], pv2[2], pv3[2];
    float  pmk[2];
    {
        const float* xr0 = x + (rowbase + l15) * E_DIM + q * 8;
        pv0[0] = *reinterpret_cast<const float4*>(xr0);
        pv1[0] = *reinterpret_cast<const float4*>(xr0 + 4);
        pv2[0] = *reinterpret_cast<const float4*>(xr0 + 32);
        pv3[0] = *reinterpret_cast<const float4*>(xr0 + 36);
        pmk[0] = mask[rowbase + l15];
        const float* xr1 = xr0 + 16 * E_DIM;
        pv0[1] = *reinterpret_cast<const float4*>(xr1);
        pv1[1] = *reinterpret_cast<const float4*>(xr1 + 4);
        pv2[1] = *reinterpret_cast<const float4*>(xr1 + 32);
        pv3[1] = *reinterpret_cast<const float4*>(xr1 + 36);
        pmk[1] = mask[rowbase + 16 + l15];
    }

    #pragma unroll 2
    for (int rt = 0; rt < NT_TILES; ++rt) {
        const int s = rt & 1;              // static after unroll-2
        const float4 u0 = pv0[s], u1 = pv1[s], u2 = pv2[s], u3 = pv3[s];
        const float  mkc = pmk[s];

        // exact fp32 row norm, tree-shaped (short dep chains)
        float sa = 0.f, sb = 0.f, sc = 0.f, sd = 0.f;
        sa = fmaf(u0.x, u0.x, sa); sa = fmaf(u0.y, u0.y, sa);
        sa = fmaf(u0.z, u0.z, sa); sa = fmaf(u0.w, u0.w, sa);
        sb = fmaf(u1.x, u1.x, sb); sb = fmaf(u1.y, u1.y, sb);
        sb = fmaf(u1.z, u1.z, sb); sb = fmaf(u1.w, u1.w, sb);
        sc = fmaf(u2.x, u2.x, sc); sc = fmaf(u2.y, u2.y, sc);
        sc = fmaf(u2.z, u2.z, sc); sc = fmaf(u2.w, u2.w, sc);
        sd = fmaf(u3.x, u3.x, sd); sd = fmaf(u3.y, u3.y, sd);
        sd = fmaf(u3.z, u3.z, sd); sd = fmaf(u3.w, u3.w, sd);
        float ss = (sa + sb) + (sc + sd);
        ss += __shfl_xor(ss, 16);
        ss += __shfl_xor(ss, 32);

        const float rbrow = __builtin_amdgcn_rcpf(1.f - ss);
        const float krow  = LN2_F * mkc;

        short8 a0 = pack8(u0, u1);
        short8 a1 = pack8(u2, u3);

        // refill slot s with tile rt+2 (u*/a* already extracted)
        if (rt + 2 < NT_TILES) {
            const float* xr = x + (rowbase + (rt + 2) * 16 + l15) * E_DIM + q * 8;
            pv0[s] = *reinterpret_cast<const float4*>(xr);
            pv1[s] = *reinterpret_cast<const float4*>(xr + 4);
            pv2[s] = *reinterpret_cast<const float4*>(xr + 32);
            pv3[s] = *reinterpret_cast<const float4*>(xr + 36);
            pmk[s] = mask[rowbase + (rt + 2) * 16 + l15];
        }

        f32x4 acc[4];
        #pragma unroll
        for (int ct = 0; ct < 4; ++ct) {
            f32x4 z = {0.f, 0.f, 0.f, 0.f};
            z = __builtin_amdgcn_mfma_f32_16x16x32_bf16(a0, bfrag[ct][0], z, 0, 0, 0);
            z = __builtin_amdgcn_mfma_f32_16x16x32_bf16(a1, bfrag[ct][1], z, 0, 0, 0);
            acc[ct] = z;
        }

        // per-row stats for this lane's 4 output rows (rows q*4+reg)
        float ar[4], rbr[4], kr[4];
        #pragma unroll
        for (int reg = 0; reg < 4; ++reg) {
            const int src = q * 4 + reg;
            ar[reg]  = __shfl(ss,    src);
            rbr[reg] = __shfl(rbrow, src);
            kr[reg]  = __shfl(krow,  src);
        }

        // epilogue -> LDS tile (row = q*4+reg, col = ct*16+l15)
        #pragma unroll
        for (int ct = 0; ct < 4; ++ct) {
            #pragma unroll
            for (int reg = 0; reg < 4; ++reg) {
                const float dot = acc[ct][reg];
                float sq = fmaf(-2.f, dot, ar[reg] + c2v[ct]);
                sq = fmaxf(sq, 0.f);
                float uu = fmaxf(sq * (rbr[reg] * rd2v[ct]), EPS_F);
                float t  = uu + __builtin_amdgcn_sqrtf(fmaf(uu, uu, uu + uu));
                const float d = __builtin_amdgcn_logf(1.f + t) * kr[reg];
                sW[(q * 4 + reg) * TP + ct * 16 + l15] = d;
                gsum[ct] += d;
            }
        }

        // drain LDS tile -> global, dwordx4, 256B-contiguous row segments
        #pragma unroll
        for (int i = 0; i < 4; ++i) {
            const int row2 = i * 4 + (lane >> 4);      // 0..15
            const int col2 = (lane & 15) * 4;          // 0..60
            float4 val = *reinterpret_cast<const float4*>(&sW[row2 * TP + col2]);
            *reinterpret_cast<float4*>(
                dist + (rowbase + rt * 16 + row2) * C_DIM + w * 64 + col2) = val;
        }
    }

    const float inv = ((const float*)(ws + WS_INVM))[b];
    #pragma unroll
    for (int ct = 0; ct < 4; ++ct) {
        float s = gsum[ct];
        s += __shfl_xor(s, 16);
        s += __shfl_xor(s, 32);
        if (q == 0)
            atomicAdd(&graph_acc[b * C_DIM + w * 64 + ct * 16 + l15], s * inv);
    }
}

extern "C" void kernel_launch(void* const* d_in, const int* in_sizes, int n_in,
                              void* d_out, int out_size, void* d_ws, size_t ws_size,
                              hipStream_t stream) {
    const float* x    = (const float*)d_in[0];
    const float* mask = (const float*)d_in[1];
    const float* cent = (const float*)d_in[2];
    float* out = (float*)d_out;

    // in_sizes = { B*N*E, B*N, C*E }; out_size = B*C + B*N*C
    const long long BN = in_sizes[1];
    const int E = in_sizes[0] / (int)BN;       // 64
    const int C = in_sizes[2] / E;             // 256
    const int B = (int)(((long long)out_size - BN * C) / C);
    const int N = (int)(BN / B);

    float* graph_acc = out;                    // (B,C)
    float* dist_out  = out + (size_t)B * C;    // (B,N,C)
    unsigned char* ws = (unsigned char*)d_ws;

    cdist_pre<<<dim3(B + 1), C_DIM, 0, stream>>>(cent, mask, ws, graph_acc, N);

    cdist_mfma<4><<<dim3(N / 64, B), 256, 0, stream>>>(
        x, mask, ws, graph_acc, dist_out, N);
}

// Round 5
// 203.426 us; speedup vs baseline: 1.5404x; 1.0263x over previous
//
#include <hip/hip_runtime.h>
#include <math.h>

// Shapes: x (B,N,64) fp32, mask (B,N), cent (256,64) fp32.
// out = concat( graph_dist (B,256), dist (B,N,256) ), fp32.
#define E_DIM 64
#define C_DIM 256
#define EPS_F 1e-6f
#define LN2_F 0.69314718056f

typedef __attribute__((ext_vector_type(8))) short short8;   // 8 bf16 = 4 VGPRs
typedef __attribute__((ext_vector_type(4))) float f32x4;

__device__ __forceinline__ unsigned short f2bf(float f) {
    unsigned int u = __float_as_uint(f);
    u += 0x7FFFu + ((u >> 16) & 1u);     // round-to-nearest-even
    return (unsigned short)(u >> 16);
}

__device__ __forceinline__ short8 pack8(float4 a, float4 b) {
    short8 h;
    h[0] = (short)f2bf(a.x); h[1] = (short)f2bf(a.y);
    h[2] = (short)f2bf(a.z); h[3] = (short)f2bf(a.w);
    h[4] = (short)f2bf(b.x); h[5] = (short)f2bf(b.y);
    h[6] = (short)f2bf(b.z); h[7] = (short)f2bf(b.w);
    return h;
}

// ws layout (bytes):
//   [0, 32768)     : B-fragments, short8 F[(ct16*2+kf)*64 + lane]
//   [32768, 33792) : c2[256]
//   [33792, 34816) : rd2[256]  = 2/(1-c2)
//   [34816, ...)   : inv_masksum[B]
#define WS_F    0
#define WS_C2   32768
#define WS_RD2  33792
#define WS_INVM 34816

// Block 0: centroid conversion + stats. Blocks 1..B: per-batch 1/sum(mask)
// and zero-init of graph_acc row b (replaces the hipMemsetAsync graph node).
__global__ __launch_bounds__(C_DIM) void cdist_pre(
    const float* __restrict__ cent,
    const float* __restrict__ mask,
    unsigned char* __restrict__ ws,
    float* __restrict__ graph_acc,
    int N)
{
    const int t = threadIdx.x;
    if (blockIdx.x == 0) {
        float r[E_DIM];
        const float* cr = cent + t * E_DIM;
        #pragma unroll
        for (int e = 0; e < E_DIM; e += 4) {
            float4 v = *reinterpret_cast<const float4*>(cr + e);
            r[e] = v.x; r[e+1] = v.y; r[e+2] = v.z; r[e+3] = v.w;
        }
        float c2 = 0.f;
        #pragma unroll
        for (int e = 0; e < E_DIM; ++e) c2 = fmaf(r[e], r[e], c2);
        ((float*)(ws + WS_C2))[t]  = c2;
        ((float*)(ws + WS_RD2))[t] = 2.f / (1.f - c2);

        const int ct16 = t >> 4, l15 = t & 15;
        short8* F = (short8*)(ws + WS_F);
        #pragma unroll
        for (int kf = 0; kf < 2; ++kf) {
            #pragma unroll
            for (int q = 0; q < 4; ++q) {
                short8 h;
                #pragma unroll
                for (int j = 0; j < 8; ++j)
                    h[j] = (short)f2bf(r[kf * 32 + q * 8 + j]);
                F[(ct16 * 2 + kf) * 64 + 16 * q + l15] = h;
            }
        }
    } else {
        const int b = blockIdx.x - 1;
        graph_acc[b * C_DIM + t] = 0.f;
        float s = 0.f;
        for (int n = t; n < N; n += C_DIM) s += mask[(size_t)b * N + n];
        #pragma unroll
        for (int off = 32; off > 0; off >>= 1) s += __shfl_down(s, off, 64);
        __shared__ float partial[4];
        if ((t & 63) == 0) partial[t >> 6] = s;
        __syncthreads();
        if (t == 0) {
            float tot = partial[0] + partial[1] + partial[2] + partial[3];
            ((float*)(ws + WS_INVM))[b] = 1.f / tot;
        }
    }
}

// Main: 256 threads (4 waves), 64 rows x 256 cols per block; wave w owns cols
// [w*64, w*64+64).
//
// SWAPPED-OPERAND MFMA (round-4 restructure): compute mfma(A=centroid_frag,
// B=x_frag). A/B fragments use the identical lane mapping, so swapping
// transposes the output: lane (l15,q) now holds rows = centroids q*4+reg,
// col = x-row l15. Therefore:
//  - per-row stats (ss/rbrow/krow for row l15) are ALREADY in-lane after the
//    2 shfl_xor norm reduce -> the 12 ds_bpermute broadcasts are gone;
//  - each lane's 4 reg values are 4 CONSECUTIVE centroid distances for one
//    x-row -> direct global dwordx4 store; the LDS transpose tile is gone
//    (LDS usage = 0, bank conflicts = 0).
// Cost: per-lane centroid tables c2/rd2 as 4x float4 each (+regs), gsum 4x4.
template<int NT_TILES>
__global__ __launch_bounds__(256, 4) void cdist_mfma(
    const float* __restrict__ x,
    const float* __restrict__ mask,
    const unsigned char* __restrict__ ws,
    float*       __restrict__ graph_acc,  // (B,C), pre-zeroed
    float*       __restrict__ dist,       // (B,N,C)
    int N)
{
    const int tid  = threadIdx.x;
    const int w    = tid >> 6;
    const int lane = tid & 63;
    const int l15  = lane & 15;
    const int q    = lane >> 4;
    const int n0   = blockIdx.x * (NT_TILES * 16);
    const int b    = blockIdx.y;

    const short8* F    = (const short8*)(ws + WS_F);
    const float*  c2w  = (const float*)(ws + WS_C2);
    const float*  rd2w = (const float*)(ws + WS_RD2);

    short8 bfrag[4][2];
    #pragma unroll
    for (int ct = 0; ct < 4; ++ct)
        #pragma unroll
        for (int kf = 0; kf < 2; ++kf)
            bfrag[ct][kf] = F[((w * 4 + ct) * 2 + kf) * 64 + lane];

    // per-lane centroid constants: centroids c0 = w*64 + ct*16 + q*4 + (0..3)
    f32x4 c2q[4], rd2q[4], gsum[4];
    #pragma unroll
    for (int ct = 0; ct < 4; ++ct) {
        const int c = w * 64 + ct * 16 + q * 4;
        c2q[ct]  = *reinterpret_cast<const f32x4*>(c2w + c);
        rd2q[ct] = *reinterpret_cast<const f32x4*>(rd2w + c);
        gsum[ct] = (f32x4){0.f, 0.f, 0.f, 0.f};
    }

    const size_t rowbase = (size_t)b * N + n0;

    // 1-deep prefetch of this lane's x-row slice (row l15, dwords q*8 block)
    const float* xr0 = x + (rowbase + l15) * E_DIM + q * 8;
    float4 v0 = *reinterpret_cast<const float4*>(xr0);
    float4 v1 = *reinterpret_cast<const float4*>(xr0 + 4);
    float4 v2 = *reinterpret_cast<const float4*>(xr0 + 32);
    float4 v3 = *reinterpret_cast<const float4*>(xr0 + 36);
    float  mk = mask[rowbase + l15];

    #pragma unroll 1
    for (int rt = 0; rt < NT_TILES; ++rt) {
        const float4 u0 = v0, u1 = v1, u2 = v2, u3 = v3;
        const float  mkc = mk;

        if (rt + 1 < NT_TILES) {
            const float* xr = x + (rowbase + (rt + 1) * 16 + l15) * E_DIM + q * 8;
            v0 = *reinterpret_cast<const float4*>(xr);
            v1 = *reinterpret_cast<const float4*>(xr + 4);
            v2 = *reinterpret_cast<const float4*>(xr + 32);
            v3 = *reinterpret_cast<const float4*>(xr + 36);
            mk = mask[rowbase + (rt + 1) * 16 + l15];
        }

        // exact fp32 row norm: each lane sums its 16 elems, then collapse q
        float sa = 0.f, sb = 0.f, sc = 0.f, sd = 0.f;
        sa = fmaf(u0.x, u0.x, sa); sa = fmaf(u0.y, u0.y, sa);
        sa = fmaf(u0.z, u0.z, sa); sa = fmaf(u0.w, u0.w, sa);
        sb = fmaf(u1.x, u1.x, sb); sb = fmaf(u1.y, u1.y, sb);
        sb = fmaf(u1.z, u1.z, sb); sb = fmaf(u1.w, u1.w, sb);
        sc = fmaf(u2.x, u2.x, sc); sc = fmaf(u2.y, u2.y, sc);
        sc = fmaf(u2.z, u2.z, sc); sc = fmaf(u2.w, u2.w, sc);
        sd = fmaf(u3.x, u3.x, sd); sd = fmaf(u3.y, u3.y, sd);
        sd = fmaf(u3.z, u3.z, sd); sd = fmaf(u3.w, u3.w, sd);
        float ss = (sa + sb) + (sc + sd);
        ss += __shfl_xor(ss, 16);
        ss += __shfl_xor(ss, 32);
        // lane (l15,q) now holds full ||x_row(l15)||^2 — exactly the row this
        // lane's outputs belong to. No broadcasts needed.

        const float rbrow = __builtin_amdgcn_rcpf(1.f - ss);
        const float krow  = LN2_F * mkc;

        const short8 a0 = pack8(u0, u1);   // x-row fragment, K 0..31
        const short8 a1 = pack8(u2, u3);   // x-row fragment, K 32..63

        float* drow = dist + (rowbase + rt * 16 + l15) * C_DIM + w * 64;

        #pragma unroll
        for (int ct = 0; ct < 4; ++ct) {
            f32x4 z = {0.f, 0.f, 0.f, 0.f};
            // swapped: A = centroid fragment, B = x fragment
            z = __builtin_amdgcn_mfma_f32_16x16x32_bf16(bfrag[ct][0], a0, z, 0, 0, 0);
            z = __builtin_amdgcn_mfma_f32_16x16x32_bf16(bfrag[ct][1], a1, z, 0, 0, 0);

            f32x4 dv;
            #pragma unroll
            for (int reg = 0; reg < 4; ++reg) {
                float sq = fmaf(-2.f, z[reg], ss + c2q[ct][reg]);
                sq = fmaxf(sq, 0.f);
                float uu = fmaxf(sq * (rbrow * rd2q[ct][reg]), EPS_F);
                float t  = uu + __builtin_amdgcn_sqrtf(fmaf(uu, uu, uu + uu));
                const float d = __builtin_amdgcn_logf(1.f + t) * krow;
                dv[reg] = d;
                gsum[ct][reg] += d;
            }
            // 4 consecutive centroids for x-row l15: direct dwordx4 store.
            // Per instruction the wave covers 16 rows x full 64B lines.
            *reinterpret_cast<f32x4*>(drow + ct * 16 + q * 4) = dv;
        }
    }

    // graph sum: reduce over the 16 x-rows (l15 dimension), then one atomic
    // per centroid from the l15==0 lanes.
    const float inv = ((const float*)(ws + WS_INVM))[b];
    #pragma unroll
    for (int ct = 0; ct < 4; ++ct) {
        #pragma unroll
        for (int reg = 0; reg < 4; ++reg) {
            float s = gsum[ct][reg];
            s += __shfl_xor(s, 1);
            s += __shfl_xor(s, 2);
            s += __shfl_xor(s, 4);
            s += __shfl_xor(s, 8);
            if (l15 == 0)
                atomicAdd(&graph_acc[b * C_DIM + w * 64 + ct * 16 + q * 4 + reg],
                          s * inv);
        }
    }
}

extern "C" void kernel_launch(void* const* d_in, const int* in_sizes, int n_in,
                              void* d_out, int out_size, void* d_ws, size_t ws_size,
                              hipStream_t stream) {
    const float* x    = (const float*)d_in[0];
    const float* mask = (const float*)d_in[1];
    const float* cent = (const float*)d_in[2];
    float* out = (float*)d_out;

    // in_sizes = { B*N*E, B*N, C*E }; out_size = B*C + B*N*C
    const long long BN = in_sizes[1];
    const int E = in_sizes[0] / (int)BN;       // 64
    const int C = in_sizes[2] / E;             // 256
    const int B = (int)(((long long)out_size - BN * C) / C);
    const int N = (int)(BN / B);

    float* graph_acc = out;                    // (B,C)
    float* dist_out  = out + (size_t)B * C;    // (B,N,C)
    unsigned char* ws = (unsigned char*)d_ws;

    cdist_pre<<<dim3(B + 1), C_DIM, 0, stream>>>(cent, mask, ws, graph_acc, N);

    cdist_mfma<4><<<dim3(N / 64, B), 256, 0, stream>>>(
        x, mask, ws, graph_acc, dist_out, N);
}

// Round 6
// 203.016 us; speedup vs baseline: 1.5435x; 1.0020x over previous
//
#include <hip/hip_runtime.h>
#include <math.h>

// Shapes: x (B,N,64) fp32, mask (B,N), cent (256,64) fp32.
// out = concat( graph_dist (B,256), dist (B,N,256) ), fp32.
#define E_DIM 64
#define C_DIM 256
#define EPS_F 1e-6f
#define LN2_F 0.69314718056f

typedef __attribute__((ext_vector_type(8))) short short8;   // 8 bf16 = 4 VGPRs
typedef __attribute__((ext_vector_type(4))) float f32x4;

__device__ __forceinline__ unsigned short f2bf(float f) {
    unsigned int u = __float_as_uint(f);
    u += 0x7FFFu + ((u >> 16) & 1u);     // round-to-nearest-even
    return (unsigned short)(u >> 16);
}

__device__ __forceinline__ short8 pack8(float4 a, float4 b) {
    short8 h;
    h[0] = (short)f2bf(a.x); h[1] = (short)f2bf(a.y);
    h[2] = (short)f2bf(a.z); h[3] = (short)f2bf(a.w);
    h[4] = (short)f2bf(b.x); h[5] = (short)f2bf(b.y);
    h[6] = (short)f2bf(b.z); h[7] = (short)f2bf(b.w);
    return h;
}

// ws layout (bytes):
//   [0, 32768)     : B-fragments, short8 F[(ct16*2+kf)*64 + lane]
//   [32768, 33792) : c2[256]
//   [33792, 34816) : rd2[256]  = 2/(1-c2)
//   [34816, ...)   : inv_masksum[B]
#define WS_F    0
#define WS_C2   32768
#define WS_RD2  33792
#define WS_INVM 34816

// Block 0: centroid conversion + stats. Blocks 1..B: per-batch 1/sum(mask)
// and zero-init of graph_acc row b (replaces the hipMemsetAsync graph node).
__global__ __launch_bounds__(C_DIM) void cdist_pre(
    const float* __restrict__ cent,
    const float* __restrict__ mask,
    unsigned char* __restrict__ ws,
    float* __restrict__ graph_acc,
    int N)
{
    const int t = threadIdx.x;
    if (blockIdx.x == 0) {
        float r[E_DIM];
        const float* cr = cent + t * E_DIM;
        #pragma unroll
        for (int e = 0; e < E_DIM; e += 4) {
            float4 v = *reinterpret_cast<const float4*>(cr + e);
            r[e] = v.x; r[e+1] = v.y; r[e+2] = v.z; r[e+3] = v.w;
        }
        float c2 = 0.f;
        #pragma unroll
        for (int e = 0; e < E_DIM; ++e) c2 = fmaf(r[e], r[e], c2);
        ((float*)(ws + WS_C2))[t]  = c2;
        ((float*)(ws + WS_RD2))[t] = 2.f / (1.f - c2);

        const int ct16 = t >> 4, l15 = t & 15;
        short8* F = (short8*)(ws + WS_F);
        #pragma unroll
        for (int kf = 0; kf < 2; ++kf) {
            #pragma unroll
            for (int q = 0; q < 4; ++q) {
                short8 h;
                #pragma unroll
                for (int j = 0; j < 8; ++j)
                    h[j] = (short)f2bf(r[kf * 32 + q * 8 + j]);
                F[(ct16 * 2 + kf) * 64 + 16 * q + l15] = h;
            }
        }
    } else {
        const int b = blockIdx.x - 1;
        graph_acc[b * C_DIM + t] = 0.f;
        float s = 0.f;
        for (int n = t; n < N; n += C_DIM) s += mask[(size_t)b * N + n];
        #pragma unroll
        for (int off = 32; off > 0; off >>= 1) s += __shfl_down(s, off, 64);
        __shared__ float partial[4];
        if ((t & 63) == 0) partial[t >> 6] = s;
        __syncthreads();
        if (t == 0) {
            float tot = partial[0] + partial[1] + partial[2] + partial[3];
            ((float*)(ws + WS_INVM))[b] = 1.f / tot;
        }
    }
}

// Main: 512 threads (8 waves), 64 rows x 256 cols per block; wave w owns
// cols [w*32, w*32+32) — HALF the per-wave state of the round-5 version.
//
// Register-pressure budget (the recurring killer this session: rounds 2/4/5
// all spilled ~130 MB/launch to scratch when resident state exceeded the
// 128-reg cap at 4 waves/SIMD):
//   bfrag 16 + c2q/rd2q 16 + gsum 8 + prefetch 17 + transients ~40 ~= 100
// < 128 -> no spills. __launch_bounds__(512) with NO min-wave arg: never
// force the allocator below its needs (round-3 lesson).
//
// Swapped-operand MFMA (round-5 win, kept): mfma(A=centroid_frag, B=x_frag)
// transposes the output so lane (q,l15) holds 4 consecutive centroids
// (q*4+reg) for x-row l15: stats are in-lane (no broadcasts), stores are
// direct 16B dwordx4 at 64B-aligned segments (no LDS transpose tile).
template<int NT_TILES>
__global__ __launch_bounds__(512) void cdist_mfma(
    const float* __restrict__ x,
    const float* __restrict__ mask,
    const unsigned char* __restrict__ ws,
    float*       __restrict__ graph_acc,  // (B,C), pre-zeroed
    float*       __restrict__ dist,       // (B,N,C)
    int N)
{
    const int tid  = threadIdx.x;
    const int w    = tid >> 6;            // 0..7
    const int lane = tid & 63;
    const int l15  = lane & 15;
    const int q    = lane >> 4;
    const int n0   = blockIdx.x * (NT_TILES * 16);
    const int b    = blockIdx.y;

    const short8* F    = (const short8*)(ws + WS_F);
    const float*  c2w  = (const float*)(ws + WS_C2);
    const float*  rd2w = (const float*)(ws + WS_RD2);

    short8 bfrag[2][2];
    #pragma unroll
    for (int ct = 0; ct < 2; ++ct)
        #pragma unroll
        for (int kf = 0; kf < 2; ++kf)
            bfrag[ct][kf] = F[((w * 2 + ct) * 2 + kf) * 64 + lane];

    // per-lane centroid constants: centroids c = w*32 + ct*16 + q*4 + (0..3)
    f32x4 c2q[2], rd2q[2], gsum[2];
    #pragma unroll
    for (int ct = 0; ct < 2; ++ct) {
        const int c = w * 32 + ct * 16 + q * 4;
        c2q[ct]  = *reinterpret_cast<const f32x4*>(c2w + c);
        rd2q[ct] = *reinterpret_cast<const f32x4*>(rd2w + c);
        gsum[ct] = (f32x4){0.f, 0.f, 0.f, 0.f};
    }

    const size_t rowbase = (size_t)b * N + n0;

    // 1-deep prefetch of this lane's x-row slice (row l15, dword chunk q*8)
    const float* xr0 = x + (rowbase + l15) * E_DIM + q * 8;
    float4 v0 = *reinterpret_cast<const float4*>(xr0);
    float4 v1 = *reinterpret_cast<const float4*>(xr0 + 4);
    float4 v2 = *reinterpret_cast<const float4*>(xr0 + 32);
    float4 v3 = *reinterpret_cast<const float4*>(xr0 + 36);
    float  mk = mask[rowbase + l15];

    #pragma unroll 1
    for (int rt = 0; rt < NT_TILES; ++rt) {
        const float4 u0 = v0, u1 = v1, u2 = v2, u3 = v3;
        const float  mkc = mk;

        if (rt + 1 < NT_TILES) {
            const float* xr = x + (rowbase + (rt + 1) * 16 + l15) * E_DIM + q * 8;
            v0 = *reinterpret_cast<const float4*>(xr);
            v1 = *reinterpret_cast<const float4*>(xr + 4);
            v2 = *reinterpret_cast<const float4*>(xr + 32);
            v3 = *reinterpret_cast<const float4*>(xr + 36);
            mk = mask[rowbase + (rt + 1) * 16 + l15];
        }

        // exact fp32 row norm: lane sums its 16 elems, collapse q via xor
        float sa = 0.f, sb = 0.f, sc = 0.f, sd = 0.f;
        sa = fmaf(u0.x, u0.x, sa); sa = fmaf(u0.y, u0.y, sa);
        sa = fmaf(u0.z, u0.z, sa); sa = fmaf(u0.w, u0.w, sa);
        sb = fmaf(u1.x, u1.x, sb); sb = fmaf(u1.y, u1.y, sb);
        sb = fmaf(u1.z, u1.z, sb); sb = fmaf(u1.w, u1.w, sb);
        sc = fmaf(u2.x, u2.x, sc); sc = fmaf(u2.y, u2.y, sc);
        sc = fmaf(u2.z, u2.z, sc); sc = fmaf(u2.w, u2.w, sc);
        sd = fmaf(u3.x, u3.x, sd); sd = fmaf(u3.y, u3.y, sd);
        sd = fmaf(u3.z, u3.z, sd); sd = fmaf(u3.w, u3.w, sd);
        float ss = (sa + sb) + (sc + sd);
        ss += __shfl_xor(ss, 16);
        ss += __shfl_xor(ss, 32);
        // lane (q,l15) holds full ||x_row(l15)||^2 — the row its outputs
        // belong to (swapped layout). No broadcasts needed.

        const float rbrow = __builtin_amdgcn_rcpf(1.f - ss);
        const float krow  = LN2_F * mkc;

        const short8 a0 = pack8(u0, u1);   // x-row fragment, K 0..31
        const short8 a1 = pack8(u2, u3);   // x-row fragment, K 32..63

        float* drow = dist + (rowbase + rt * 16 + l15) * C_DIM + w * 32;

        #pragma unroll
        for (int ct = 0; ct < 2; ++ct) {
            f32x4 z = {0.f, 0.f, 0.f, 0.f};
            // swapped: A = centroid fragment, B = x fragment
            z = __builtin_amdgcn_mfma_f32_16x16x32_bf16(bfrag[ct][0], a0, z, 0, 0, 0);
            z = __builtin_amdgcn_mfma_f32_16x16x32_bf16(bfrag[ct][1], a1, z, 0, 0, 0);

            f32x4 dv;
            #pragma unroll
            for (int reg = 0; reg < 4; ++reg) {
                float sq = fmaf(-2.f, z[reg], ss + c2q[ct][reg]);
                sq = fmaxf(sq, 0.f);
                float uu = fmaxf(sq * (rbrow * rd2q[ct][reg]), EPS_F);
                float t  = uu + __builtin_amdgcn_sqrtf(fmaf(uu, uu, uu + uu));
                const float d = __builtin_amdgcn_logf(1.f + t) * krow;
                dv[reg] = d;
                gsum[ct][reg] += d;
            }
            // 4 consecutive centroids for x-row l15: 64B-aligned dwordx4.
            *reinterpret_cast<f32x4*>(drow + ct * 16 + q * 4) = dv;
        }
    }

    // graph sum: reduce over the 16 x-rows (l15 bits), one atomic per
    // centroid from the l15==0 lanes.
    const float inv = ((const float*)(ws + WS_INVM))[b];
    #pragma unroll
    for (int ct = 0; ct < 2; ++ct) {
        #pragma unroll
        for (int reg = 0; reg < 4; ++reg) {
            float s = gsum[ct][reg];
            s += __shfl_xor(s, 1);
            s += __shfl_xor(s, 2);
            s += __shfl_xor(s, 4);
            s += __shfl_xor(s, 8);
            if (l15 == 0)
                atomicAdd(&graph_acc[b * C_DIM + w * 32 + ct * 16 + q * 4 + reg],
                          s * inv);
        }
    }
}

extern "C" void kernel_launch(void* const* d_in, const int* in_sizes, int n_in,
                              void* d_out, int out_size, void* d_ws, size_t ws_size,
                              hipStream_t stream) {
    const float* x    = (const float*)d_in[0];
    const float* mask = (const float*)d_in[1];
    const float* cent = (const float*)d_in[2];
    float* out = (float*)d_out;

    // in_sizes = { B*N*E, B*N, C*E }; out_size = B*C + B*N*C
    const long long BN = in_sizes[1];
    const int E = in_sizes[0] / (int)BN;       // 64
    const int C = in_sizes[2] / E;             // 256
    const int B = (int)(((long long)out_size - BN * C) / C);
    const int N = (int)(BN / B);

    float* graph_acc = out;                    // (B,C)
    float* dist_out  = out + (size_t)B * C;    // (B,N,C)
    unsigned char* ws = (unsigned char*)d_ws;

    cdist_pre<<<dim3(B + 1), C_DIM, 0, stream>>>(cent, mask, ws, graph_acc, N);

    cdist_mfma<4><<<dim3(N / 64, B), 512, 0, stream>>>(
        x, mask, ws, graph_acc, dist_out, N);
}

// Round 7
// 177.275 us; speedup vs baseline: 1.7677x; 1.1452x over previous
//
#include <hip/hip_runtime.h>
#include <math.h>

// Shapes: x (B,N,64) fp32, mask (B,N), cent (256,64) fp32.
// out = concat( graph_dist (B,256), dist (B,N,256) ), fp32.
// ROUND 7: re-anchor on the round-0 structure (best measured total, 179.1us).
// Only two near-zero-risk deltas vs round 0:
//   (1) graph_acc zeroing folded into cdist_pre (one fewer dispatch),
//   (2) tree-shaped row-norm reduction (same ops, shorter dep chain).
#define E_DIM 64
#define C_DIM 256
#define EPS_F 1e-6f
#define LN2_F 0.69314718056f
#define TP    68            // padded LDS row stride (dwords): 2-way bank alias only

typedef __attribute__((ext_vector_type(8))) short short8;   // 8 bf16 = 4 VGPRs
typedef __attribute__((ext_vector_type(4))) float f32x4;

__device__ __forceinline__ unsigned short f2bf(float f) {
    unsigned int u = __float_as_uint(f);
    u += 0x7FFFu + ((u >> 16) & 1u);     // round-to-nearest-even
    return (unsigned short)(u >> 16);
}

__device__ __forceinline__ short8 pack8(float4 a, float4 b) {
    short8 h;
    h[0] = (short)f2bf(a.x); h[1] = (short)f2bf(a.y);
    h[2] = (short)f2bf(a.z); h[3] = (short)f2bf(a.w);
    h[4] = (short)f2bf(b.x); h[5] = (short)f2bf(b.y);
    h[6] = (short)f2bf(b.z); h[7] = (short)f2bf(b.w);
    return h;
}

// ws layout (bytes):
//   [0, 32768)     : B-fragments, short8 F[(ct16*2+kf)*64 + lane]
//   [32768, 33792) : c2[256]
//   [33792, 34816) : rd2[256]  = 2/(1-c2)
//   [34816, ...)   : inv_masksum[B]
#define WS_F    0
#define WS_C2   32768
#define WS_RD2  33792
#define WS_INVM 34816

// Block 0: centroid conversion + stats. Blocks 1..B: per-batch 1/sum(mask)
// and zero-init of graph_acc row b (replaces the hipMemsetAsync graph node).
__global__ __launch_bounds__(C_DIM) void cdist_pre(
    const float* __restrict__ cent,
    const float* __restrict__ mask,
    unsigned char* __restrict__ ws,
    float* __restrict__ graph_acc,
    int N)
{
    const int t = threadIdx.x;
    if (blockIdx.x == 0) {
        float r[E_DIM];
        const float* cr = cent + t * E_DIM;
        #pragma unroll
        for (int e = 0; e < E_DIM; e += 4) {
            float4 v = *reinterpret_cast<const float4*>(cr + e);
            r[e] = v.x; r[e+1] = v.y; r[e+2] = v.z; r[e+3] = v.w;
        }
        float c2 = 0.f;
        #pragma unroll
        for (int e = 0; e < E_DIM; ++e) c2 = fmaf(r[e], r[e], c2);
        ((float*)(ws + WS_C2))[t]  = c2;
        ((float*)(ws + WS_RD2))[t] = 2.f / (1.f - c2);

        const int ct16 = t >> 4, l15 = t & 15;
        short8* F = (short8*)(ws + WS_F);
        #pragma unroll
        for (int kf = 0; kf < 2; ++kf) {
            #pragma unroll
            for (int q = 0; q < 4; ++q) {
                short8 h;
                #pragma unroll
                for (int j = 0; j < 8; ++j)
                    h[j] = (short)f2bf(r[kf * 32 + q * 8 + j]);
                F[(ct16 * 2 + kf) * 64 + 16 * q + l15] = h;
            }
        }
    } else {
        const int b = blockIdx.x - 1;
        graph_acc[b * C_DIM + t] = 0.f;
        float s = 0.f;
        for (int n = t; n < N; n += C_DIM) s += mask[(size_t)b * N + n];
        #pragma unroll
        for (int off = 32; off > 0; off >>= 1) s += __shfl_down(s, off, 64);
        __shared__ float partial[4];
        if ((t & 63) == 0) partial[t >> 6] = s;
        __syncthreads();
        if (t == 0) {
            float tot = partial[0] + partial[1] + partial[2] + partial[3];
            ((float*)(ws + WS_INVM))[b] = 1.f / tot;
        }
    }
}

// Main: 256 threads (4 waves), 64 rows x 256 cols per block. Wave w owns cols
// [w*64, w*64+64). Output tile transposed through a private per-wave LDS tile
// so global stores are dwordx4 with 256B-contiguous row segments.
// (Round-0 structure, verified best total.)
__global__ __launch_bounds__(256, 4) void cdist_mfma(
    const float* __restrict__ x,
    const float* __restrict__ mask,
    const unsigned char* __restrict__ ws,
    float*       __restrict__ graph_acc,  // (B,C), pre-zeroed
    float*       __restrict__ dist,       // (B,N,C)
    int N)
{
    const int tid  = threadIdx.x;
    const int w    = tid >> 6;
    const int lane = tid & 63;
    const int l15  = lane & 15;
    const int q    = lane >> 4;
    const int n0   = blockIdx.x * 64;
    const int b    = blockIdx.y;

    __shared__ __align__(16) float sT[4][16 * TP];   // per-wave transpose tile

    const short8* F    = (const short8*)(ws + WS_F);
    const float*  c2w  = (const float*)(ws + WS_C2);
    const float*  rd2w = (const float*)(ws + WS_RD2);

    short8 bfrag[4][2];
    #pragma unroll
    for (int ct = 0; ct < 4; ++ct)
        #pragma unroll
        for (int kf = 0; kf < 2; ++kf)
            bfrag[ct][kf] = F[((w * 4 + ct) * 2 + kf) * 64 + lane];

    float c2v[4], rd2v[4], gsum[4];
    #pragma unroll
    for (int ct = 0; ct < 4; ++ct) {
        const int c = w * 64 + ct * 16 + l15;
        c2v[ct] = c2w[c]; rd2v[ct] = rd2w[c]; gsum[ct] = 0.f;
    }

    const size_t rowbase = (size_t)b * N + n0;
    float* sW = sT[w];

    // prefetch row-tile 0
    const float* xr0 = x + (rowbase + l15) * E_DIM + q * 8;
    float4 v0 = *reinterpret_cast<const float4*>(xr0);
    float4 v1 = *reinterpret_cast<const float4*>(xr0 + 4);
    float4 v2 = *reinterpret_cast<const float4*>(xr0 + 32);
    float4 v3 = *reinterpret_cast<const float4*>(xr0 + 36);
    float  mk = mask[rowbase + l15];

    #pragma unroll 1
    for (int rt = 0; rt < 4; ++rt) {
        // current tile regs
        float4 u0 = v0, u1 = v1, u2 = v2, u3 = v3;
        float  mkc = mk;

        // issue next tile's loads (overlap with compute below)
        if (rt < 3) {
            const float* xr = x + (rowbase + (rt + 1) * 16 + l15) * E_DIM + q * 8;
            v0 = *reinterpret_cast<const float4*>(xr);
            v1 = *reinterpret_cast<const float4*>(xr + 4);
            v2 = *reinterpret_cast<const float4*>(xr + 32);
            v3 = *reinterpret_cast<const float4*>(xr + 36);
            mk = mask[rowbase + (rt + 1) * 16 + l15];
        }

        // exact fp32 row norm, tree-shaped (short dep chains)
        float sa = 0.f, sb = 0.f, sc = 0.f, sd = 0.f;
        sa = fmaf(u0.x, u0.x, sa); sa = fmaf(u0.y, u0.y, sa);
        sa = fmaf(u0.z, u0.z, sa); sa = fmaf(u0.w, u0.w, sa);
        sb = fmaf(u1.x, u1.x, sb); sb = fmaf(u1.y, u1.y, sb);
        sb = fmaf(u1.z, u1.z, sb); sb = fmaf(u1.w, u1.w, sb);
        sc = fmaf(u2.x, u2.x, sc); sc = fmaf(u2.y, u2.y, sc);
        sc = fmaf(u2.z, u2.z, sc); sc = fmaf(u2.w, u2.w, sc);
        sd = fmaf(u3.x, u3.x, sd); sd = fmaf(u3.y, u3.y, sd);
        sd = fmaf(u3.z, u3.z, sd); sd = fmaf(u3.w, u3.w, sd);
        float ss = (sa + sb) + (sc + sd);
        ss += __shfl_xor(ss, 16);
        ss += __shfl_xor(ss, 32);

        const float rbrow = __builtin_amdgcn_rcpf(1.f - ss);
        const float krow  = LN2_F * mkc;

        short8 a0 = pack8(u0, u1);
        short8 a1 = pack8(u2, u3);

        f32x4 acc[4];
        #pragma unroll
        for (int ct = 0; ct < 4; ++ct) {
            f32x4 z = {0.f, 0.f, 0.f, 0.f};
            z = __builtin_amdgcn_mfma_f32_16x16x32_bf16(a0, bfrag[ct][0], z, 0, 0, 0);
            z = __builtin_amdgcn_mfma_f32_16x16x32_bf16(a1, bfrag[ct][1], z, 0, 0, 0);
            acc[ct] = z;
        }

        // per-row stats for this lane's 4 output rows (rows q*4+reg)
        float ar[4], rbr[4], kr[4];
        #pragma unroll
        for (int reg = 0; reg < 4; ++reg) {
            const int src = q * 4 + reg;
            ar[reg]  = __shfl(ss,    src);
            rbr[reg] = __shfl(rbrow, src);
            kr[reg]  = __shfl(krow,  src);
        }

        // epilogue -> LDS tile (row = q*4+reg, col = ct*16+l15)
        #pragma unroll
        for (int ct = 0; ct < 4; ++ct) {
            #pragma unroll
            for (int reg = 0; reg < 4; ++reg) {
                const float dot = acc[ct][reg];
                float sq = fmaf(-2.f, dot, ar[reg] + c2v[ct]);
                sq = fmaxf(sq, 0.f);
                float uu = fmaxf(sq * (rbr[reg] * rd2v[ct]), EPS_F);
                float t  = uu + __builtin_amdgcn_sqrtf(fmaf(uu, uu, uu + uu));
                const float d = __builtin_amdgcn_logf(1.f + t) * kr[reg];
                sW[(q * 4 + reg) * TP + ct * 16 + l15] = d;
                gsum[ct] += d;
            }
        }

        // drain LDS tile -> global, dwordx4, 256B-contiguous row segments
        #pragma unroll
        for (int i = 0; i < 4; ++i) {
            const int row2 = i * 4 + (lane >> 4);      // 0..15
            const int col2 = (lane & 15) * 4;          // 0..60
            float4 val = *reinterpret_cast<const float4*>(&sW[row2 * TP + col2]);
            *reinterpret_cast<float4*>(
                dist + (rowbase + rt * 16 + row2) * C_DIM + w * 64 + col2) = val;
        }
    }

    const float inv = ((const float*)(ws + WS_INVM))[b];
    #pragma unroll
    for (int ct = 0; ct < 4; ++ct) {
        float s = gsum[ct];
        s += __shfl_xor(s, 16);
        s += __shfl_xor(s, 32);
        if (q == 0)
            atomicAdd(&graph_acc[b * C_DIM + w * 64 + ct * 16 + l15], s * inv);
    }
}

extern "C" void kernel_launch(void* const* d_in, const int* in_sizes, int n_in,
                              void* d_out, int out_size, void* d_ws, size_t ws_size,
                              hipStream_t stream) {
    const float* x    = (const float*)d_in[0];
    const float* mask = (const float*)d_in[1];
    const float* cent = (const float*)d_in[2];
    float* out = (float*)d_out;

    // in_sizes = { B*N*E, B*N, C*E }; out_size = B*C + B*N*C
    const long long BN = in_sizes[1];
    const int E = in_sizes[0] / (int)BN;       // 64
    const int C = in_sizes[2] / E;             // 256
    const int B = (int)(((long long)out_size - BN * C) / C);
    const int N = (int)(BN / B);

    float* graph_acc = out;                    // (B,C)
    float* dist_out  = out + (size_t)B * C;    // (B,N,C)
    unsigned char* ws = (unsigned char*)d_ws;

    cdist_pre<<<dim3(B + 1), C_DIM, 0, stream>>>(cent, mask, ws, graph_acc, N);

    cdist_mfma<<<dim3(N / 64, B), 256, 0, stream>>>(
        x, mask, ws, graph_acc, dist_out, N);
}